// Round 12
// baseline (758.362 us; speedup 1.0000x reference)
//
#include <hip/hip_runtime.h>
#include <math.h>

#define Bb 16
#define Cc 256
#define Nn 1024
#define Mm 256
#define NHh 8
#define HDd 32
#define HIDh 24
#define NMs (Nn*Mm)
#define TTB 8
#define CHUNK 8
#define EPSf 1e-5f
#define SCALEf 0.17677669529663687f   // 1/sqrt(32)
#define STP 32   // stats padding stride (floats) = 128B cacheline

__device__ __forceinline__ float wave_sum(float v){
#pragma unroll
  for (int off=32; off; off>>=1) v += __shfl_xor(v, off, 64);
  return v;
}
__device__ __forceinline__ float wave_max(float v){
#pragma unroll
  for (int off=32; off; off>>=1) v = fmaxf(v, __shfl_xor(v, off, 64));
  return v;
}
__device__ __forceinline__ float swish_(float x){ return x / (1.f + __expf(-x)); }
__device__ __forceinline__ unsigned short f2bf(float f){
  unsigned u = __float_as_uint(f);
  u += 0x7fffu + ((u >> 16) & 1u);          // round-to-nearest-even
  return (unsigned short)(u >> 16);
}
__device__ __forceinline__ float bfup(unsigned short s){ return __uint_as_float(((unsigned)s) << 16); }
__device__ __forceinline__ float bflo(unsigned u){ return __uint_as_float(u << 16); }
__device__ __forceinline__ float bfhi(unsigned u){ return __uint_as_float(u & 0xffff0000u); }

// ------------- GEMM: out[b,i,j] = sum_k A[b,k,i]*W[j,k] (+bias) -------------
template<int MODE>
__launch_bounds__(256)
__global__ void gemm_tn(const float* __restrict__ A, const float* __restrict__ W,
                        const float* __restrict__ bias, float* __restrict__ O1,
                        float* __restrict__ O2, int Kdim, long sAb, int sAk, int sAi)
{
  __shared__ __align__(16) float As[16][68];
  __shared__ __align__(16) float Ws[16][68];
  const int b  = blockIdx.z;
  const int i0 = blockIdx.x * 64;
  const int j0 = blockIdx.y * 64;
  const int tid = threadIdx.x;
  const int tx = tid & 15, ty = tid >> 4;
  const float* Ab = A + (long)b * sAb;
  float acc[4][4] = {};
  for (int k0 = 0; k0 < Kdim; k0 += 16) {
#pragma unroll
    for (int t = 0; t < 4; t++) {
      int idx = tid + t * 256;
      int kk, ii;
      if (sAi == 1) { kk = idx >> 6; ii = idx & 63; }
      else          { ii = idx >> 4; kk = idx & 15; }
      As[kk][ii] = Ab[(long)(k0 + kk) * sAk + (long)(i0 + ii) * sAi];
    }
#pragma unroll
    for (int t = 0; t < 4; t++) {
      int idx = tid + t * 256;
      int jj = idx & 63, kk = idx >> 6;
      Ws[kk][jj] = W[(long)(j0 + jj) * Kdim + (k0 + kk)];
    }
    __syncthreads();
#pragma unroll
    for (int kk = 0; kk < 16; kk++) {
      const float4 av = *(const float4*)&As[kk][tx * 4];
      const float4 wv = *(const float4*)&Ws[kk][ty * 4];
      const float a4[4] = {av.x, av.y, av.z, av.w};
      const float w4[4] = {wv.x, wv.y, wv.z, wv.w};
#pragma unroll
      for (int u = 0; u < 4; u++)
#pragma unroll
        for (int v = 0; v < 4; v++)
          acc[u][v] = fmaf(a4[u], w4[v], acc[u][v]);
    }
    __syncthreads();
  }
#pragma unroll
  for (int v = 0; v < 4; v++) {
    const int j = j0 + ty * 4 + v;
    if (MODE == 0) {
      const int h = j >> 5, d = j & 31;
      float4 r4 = make_float4(acc[0][v], acc[1][v], acc[2][v], acc[3][v]);
      *(float4*)&O1[(((long)b * NHh + h) * HDd + d) * Nn + i0 + tx * 4] = r4;
    } else if (MODE == 2) {
      const float bb = bias[j];
      float4 r4 = make_float4(acc[0][v] + bb, acc[1][v] + bb, acc[2][v] + bb, acc[3][v] + bb);
      *(float4*)&O1[((long)b * Cc + j) * Nn + i0 + tx * 4] = r4;
    } else {
      const int two = j >> 8, jj = j & 255;
      const int h = jj >> 5, d = jj & 31;
      float* p = two ? O2 : O1;
#pragma unroll
      for (int u = 0; u < 4; u++)
        p[(((long)b * NHh + h) * Mm + (i0 + tx * 4 + u)) * HDd + d] = acc[u][v];
    }
  }
}

// ------------- sv[b,h,d] = sum_m v[b,h,m,d] -------------
__launch_bounds__(256)
__global__ void compute_sv(const float* __restrict__ vb, float* __restrict__ sv)
{
  __shared__ float red[256];
  const int bh = blockIdx.x, tid = threadIdx.x;
  const int d = tid & 31, ch = tid >> 5;
  const float* vp = vb + (long)bh * Mm * HDd;
  float s = 0.f;
  for (int m = ch; m < Mm; m += 8) s += vp[m * HDd + d];
  red[tid] = s;
  __syncthreads();
  if (tid < 32) {
    float t = 0.f;
#pragma unroll
    for (int cc = 0; cc < 8; cc++) t += red[cc * 32 + tid];
    sv[(long)bh * HDd + tid] = t;
  }
}

// ------------- scores + softmax -> attn (bf16) -------------
__launch_bounds__(256)
__global__ void attn_softmax(const float* __restrict__ qhT, const float* __restrict__ kb,
                             const float* __restrict__ rpb, unsigned short* __restrict__ attn)
{
  __shared__ __align__(16) float Ks[Mm][36];
  __shared__ __align__(16) float qs[32][36];
  const int b = blockIdx.z, h = blockIdx.y, n0 = blockIdx.x * 32;
  const int tid = threadIdx.x;
  const float* kp = kb + ((long)b * NHh + h) * Mm * HDd;
#pragma unroll
  for (int u = 0; u < 8; u++) {
    const int f = tid + u * 256;
    const int m = f >> 3, d = (f & 7) * 4;
    *(float4*)&Ks[m][d] = *(const float4*)&kp[m * HDd + d];
  }
  const float* qp = qhT + ((long)b * NHh + h) * HDd * Nn;
#pragma unroll
  for (int u = 0; u < 4; u++) {
    const int idx = tid + u * 256;
    const int nn = idx & 31, dd = idx >> 5;
    qs[nn][dd] = qp[(long)dd * Nn + n0 + nn];
  }
  __syncthreads();
  const int lane = tid & 63, w = tid >> 6;
  const int r0 = w * 8;
  float s[8][4] = {};
#pragma unroll
  for (int dq = 0; dq < 8; dq++) {
    float4 k4[4];
#pragma unroll
    for (int j = 0; j < 4; j++) k4[j] = *(const float4*)&Ks[lane + j * 64][dq * 4];
#pragma unroll
    for (int r = 0; r < 8; r++) {
      const float4 q4 = *(const float4*)&qs[r0 + r][dq * 4];
#pragma unroll
      for (int j = 0; j < 4; j++) {
        s[r][j] = fmaf(q4.x, k4[j].x, s[r][j]);
        s[r][j] = fmaf(q4.y, k4[j].y, s[r][j]);
        s[r][j] = fmaf(q4.z, k4[j].z, s[r][j]);
        s[r][j] = fmaf(q4.w, k4[j].w, s[r][j]);
      }
    }
  }
#pragma unroll
  for (int r = 0; r < 8; r++) {
    const int n = n0 + r0 + r;
    const float* rp = rpb + (long)n * Mm;
    float sc[4];
#pragma unroll
    for (int j = 0; j < 4; j++) sc[j] = fmaf(s[r][j], SCALEf, rp[lane + j * 64]);
    float mx = fmaxf(fmaxf(sc[0], sc[1]), fmaxf(sc[2], sc[3]));
    mx = wave_max(mx);
    float e[4], sum = 0.f;
#pragma unroll
    for (int j = 0; j < 4; j++) { e[j] = __expf(sc[j] - mx); sum += e[j]; }
    sum = wave_sum(sum);
    const float inv = 1.f / sum;
    unsigned short* ap = attn + (((long)b * NHh + h) * Nn + n) * Mm;
#pragma unroll
    for (int j = 0; j < 4; j++) ap[lane + j * 64] = f2bf(e[j] * inv);
  }
}

// ------------- Gram matrix G[b][36*STP] (line-spread atomics) -------------
__launch_bounds__(256)
__global__ void gram_stats(const unsigned short* __restrict__ attn, float* __restrict__ G)
{
  __shared__ float red[36][4];
  const int b = blockIdx.y, tid = threadIdx.x;
  const unsigned short* ap = attn + (long)b * NHh * NMs + (long)blockIdx.x * 2048 + tid * 8;
  float a[8][8];
#pragma unroll
  for (int h = 0; h < 8; h++) {
    const uint4 v = *(const uint4*)&ap[(long)h * NMs];
    a[h][0] = bflo(v.x); a[h][1] = bfhi(v.x); a[h][2] = bflo(v.y); a[h][3] = bfhi(v.y);
    a[h][4] = bflo(v.z); a[h][5] = bfhi(v.z); a[h][6] = bflo(v.w); a[h][7] = bfhi(v.w);
  }
  float g[36];
  int t = 0;
#pragma unroll
  for (int i = 0; i < 8; i++)
#pragma unroll
    for (int j = i; j < 8; j++, t++) {
      float s = 0.f;
#pragma unroll
      for (int m = 0; m < 8; m++) s = fmaf(a[i][m], a[j][m], s);
      g[t] = s;
    }
  const int lane = tid & 63, wid = tid >> 6;
#pragma unroll
  for (int t2 = 0; t2 < 36; t2++) {
    const float s = wave_sum(g[t2]);
    if (lane == 0) red[t2][wid] = s;
  }
  __syncthreads();
  if (tid < 36)
    atomicAdd(&G[((long)b * 36 + tid) * STP],
              red[tid][0] + red[tid][1] + red[tid][2] + red[tid][3]);
}

// ------------- pass B: expand+gn1(from G)+swish -> conv3x3 -> x2(bf16) + gn2 stats ----
// One-shot staging (TTB=8 -> 40 KB LDS, 1024 blocks, ~2 blocks/CU resident),
// ONE barrier, channel-pair (ch0/ch1 adjacent) arithmetic for v_pk_fma packing.
__launch_bounds__(768)
__global__ void dla_pass_b(const unsigned short* __restrict__ attn,
                           const float* __restrict__ Wexp,
                           const float* __restrict__ g1, const float* __restrict__ b1,
                           const float* __restrict__ G, const float* __restrict__ Wdw,
                           unsigned short* __restrict__ x2, float* __restrict__ stats2c, int b0)
{
  __shared__ __align__(16) unsigned short sl[TTB + 2][NHh][Mm];   // 10 x 4 KB = 40 KB
  const int tid = threadIdx.x;
  const int wv = tid >> 6, lane = tid & 63;
  const int bc = blockIdx.y, b = b0 + bc;
  const int n0 = blockIdx.x * TTB;
  const int c0 = wv * 2;
  const int g = c0 >> 3;
  // gn1 stats from Gram matrix (mean exact: softmax rows sum to 1)
  float mu, rs;
  {
    const float* Gb = G + (long)b * 36 * STP;
    float sum = 0.f, sumsq = 0.f;
    for (int c = g * 8; c < g * 8 + 8; c++) {
      float w[8];
#pragma unroll
      for (int h = 0; h < 8; h++) w[h] = Wexp[c * 8 + h];
      float wsu = 0.f;
#pragma unroll
      for (int h = 0; h < 8; h++) wsu += w[h];
      sum += wsu;
      float s2 = 0.f;
      int t = 0;
#pragma unroll
      for (int i = 0; i < 8; i++)
#pragma unroll
        for (int j = i; j < 8; j++, t++) {
          const float f = (i == j) ? 1.f : 2.f;
          s2 = fmaf(f * w[i] * w[j], Gb[t * STP], s2);
        }
      sumsq += s2;
    }
    const float cnt = 8.f * NMs;
    mu = sum * ((float)Nn / cnt);
    const float var = sumsq / cnt - mu * mu;
    rs = rsqrtf(var + EPSf);
  }
  // channel-pair weights: index 0 -> c0, index 1 -> c0+1
  float we0[8], we1[8], wd0[9], wd1[9], B10, B11;
  {
    const float A10 = rs * g1[c0], A11 = rs * g1[c0 + 1];
    B10 = b1[c0] - mu * A10;  B11 = b1[c0 + 1] - mu * A11;
#pragma unroll
    for (int h = 0; h < NHh; h++) {
      we0[h] = Wexp[c0 * NHh + h] * A10;
      we1[h] = Wexp[(c0 + 1) * NHh + h] * A11;
    }
#pragma unroll
    for (int k = 0; k < 9; k++) {
      wd0[k] = Wdw[c0 * 9 + k];
      wd1[k] = Wdw[(c0 + 1) * 9 + k];
    }
  }
  // stage all TTB+2 rows: (TTB+2)*8*32 uint4s, coalesced, one barrier
  const unsigned short* ab = attn + (long)b * NHh * NMs;
  const int TOT4 = (TTB + 2) * 256;
#pragma unroll
  for (int k = 0; k < (TOT4 + 767) / 768; k++) {
    const int f = tid + k * 768;
    if (f < TOT4) {
      const int row = f >> 8;
      const int rem = f & 255;
      const int h = rem >> 5, seg = rem & 31;
      const int nn = n0 - 1 + row;
      uint4 v = make_uint4(0u, 0u, 0u, 0u);
      if (nn >= 0 && nn < Nn)
        v = *(const uint4*)&ab[(long)h * NMs + (long)nn * Mm + seg * 8];
      *(uint4*)&sl[row][h][seg * 8] = v;
    }
  }
  __syncthreads();   // the only barrier
  float s10[4] = {}, s11[4] = {}, s20[4] = {}, s21[4] = {};
  float sm0 = 0.f, sm1 = 0.f, sq0 = 0.f, sq1 = 0.f;
  for (int r = -1; r <= TTB; r++) {
    const int nn = n0 + r;
    const bool rowv = (nn >= 0 && nn < Nn);
    float xp0[4], xp1[4];
    if (rowv) {
#pragma unroll
      for (int mi = 0; mi < 4; mi++) { xp0[mi] = B10; xp1[mi] = B11; }
#pragma unroll
      for (int h = 0; h < NHh; h++) {
        const ushort4 v = *(const ushort4*)&sl[r + 1][h][lane * 4];
        const float a0 = bfup(v.x), a1 = bfup(v.y), a2 = bfup(v.z), a3 = bfup(v.w);
        const float w0 = we0[h], w1 = we1[h];
        xp0[0] = fmaf(w0, a0, xp0[0]); xp1[0] = fmaf(w1, a0, xp1[0]);
        xp0[1] = fmaf(w0, a1, xp0[1]); xp1[1] = fmaf(w1, a1, xp1[1]);
        xp0[2] = fmaf(w0, a2, xp0[2]); xp1[2] = fmaf(w1, a2, xp1[2]);
        xp0[3] = fmaf(w0, a3, xp0[3]); xp1[3] = fmaf(w1, a3, xp1[3]);
      }
#pragma unroll
      for (int mi = 0; mi < 4; mi++) { xp0[mi] = swish_(xp0[mi]); xp1[mi] = swish_(xp1[mi]); }
    } else {
#pragma unroll
      for (int mi = 0; mi < 4; mi++) { xp0[mi] = 0.f; xp1[mi] = 0.f; }
    }
    float xl0 = __shfl_up(xp0[3], 1), xl1 = __shfl_up(xp1[3], 1);
    float xr0 = __shfl_down(xp0[0], 1), xr1 = __shfl_down(xp1[0], 1);
    if (lane == 0)  { xl0 = 0.f; xl1 = 0.f; }
    if (lane == 63) { xr0 = 0.f; xr1 = 0.f; }
    const float L0[4] = {xl0, xp0[0], xp0[1], xp0[2]};
    const float L1[4] = {xl1, xp1[0], xp1[1], xp1[2]};
    const float R0[4] = {xp0[1], xp0[2], xp0[3], xr0};
    const float R1[4] = {xp1[1], xp1[2], xp1[3], xr1};
    float y0[4], y1[4];
#pragma unroll
    for (int mi = 0; mi < 4; mi++) {
      const float u00 = wd0[0]*L0[mi] + wd0[1]*xp0[mi] + wd0[2]*R0[mi];
      const float u01 = wd1[0]*L1[mi] + wd1[1]*xp1[mi] + wd1[2]*R1[mi];
      const float u10 = wd0[3]*L0[mi] + wd0[4]*xp0[mi] + wd0[5]*R0[mi];
      const float u11 = wd1[3]*L1[mi] + wd1[4]*xp1[mi] + wd1[5]*R1[mi];
      const float u20 = wd0[6]*L0[mi] + wd0[7]*xp0[mi] + wd0[8]*R0[mi];
      const float u21 = wd1[6]*L1[mi] + wd1[7]*xp1[mi] + wd1[8]*R1[mi];
      y0[mi] = s20[mi] + u20;  y1[mi] = s21[mi] + u21;
      s20[mi] = s10[mi] + u10; s21[mi] = s11[mi] + u11;
      s10[mi] = u00;           s11[mi] = u01;
    }
    if (r >= 1) {
#pragma unroll
      for (int mi = 0; mi < 4; mi++) {
        sm0 += y0[mi]; sq0 = fmaf(y0[mi], y0[mi], sq0);
        sm1 += y1[mi]; sq1 = fmaf(y1[mi], y1[mi], sq1);
      }
      const int nw = n0 + r - 1;
      ushort4 st0, st1;
      st0.x = f2bf(y0[0]); st0.y = f2bf(y0[1]); st0.z = f2bf(y0[2]); st0.w = f2bf(y0[3]);
      st1.x = f2bf(y1[0]); st1.y = f2bf(y1[1]); st1.z = f2bf(y1[2]); st1.w = f2bf(y1[3]);
      unsigned short* xq = x2 + ((long)(bc * Nn + nw) * HIDh + c0) * Mm + lane * 4;
      *(ushort4*)xq = st0;
      *(ushort4*)(xq + Mm) = st1;
    }
  }
  {
    const float vs0 = wave_sum(sm0), vq0 = wave_sum(sq0);
    const float vs1 = wave_sum(sm1), vq1 = wave_sum(sq1);
    if (lane == 0) {
      atomicAdd(&stats2c[((long)b * HIDh + c0) * STP], vs0);
      atomicAdd(&stats2c[((long)b * HIDh + c0) * STP + 1], vq0);
      atomicAdd(&stats2c[((long)b * HIDh + c0 + 1) * STP], vs1);
      atomicAdd(&stats2c[((long)b * HIDh + c0 + 1) * STP + 1], vq1);
    }
  }
}

// ------------- pass C: gn2+swish + 1x1 reduce -> a2(bf16) + partial gn3 stats -------
__launch_bounds__(256)
__global__ void dla_pass_c(const unsigned short* __restrict__ x2, const float* __restrict__ g2,
                           const float* __restrict__ b2, const float* __restrict__ stats2c,
                           const float* __restrict__ Wred, unsigned short* __restrict__ a2,
                           float* __restrict__ partial3, int b0)
{
  __shared__ float wA[HIDh], wB[HIDh], wrs[HIDh][NHh];
  __shared__ float red2[2][4];
  const int tid = threadIdx.x;
  const int wv = tid >> 6, lane = tid & 63;
  const int bc = blockIdx.y, b = b0 + bc;
  if (tid < HIDh) {
    const int c = tid, g = c >> 3;
    float s = 0.f, q = 0.f;
#pragma unroll
    for (int cc = 0; cc < 8; cc++) {
      s += stats2c[((long)b * HIDh + g * 8 + cc) * STP];
      q += stats2c[((long)b * HIDh + g * 8 + cc) * STP + 1];
    }
    const float cnt = 8.f * NMs;
    const float mu = s / cnt;
    const float var = q / cnt - mu * mu;
    const float A2 = rsqrtf(var + EPSf) * g2[c];
    wA[c] = A2; wB[c] = b2[c] - mu * A2;
  }
  if (tid < HIDh * NHh) {
    const int c = tid >> 3, h = tid & 7;
    wrs[c][h] = Wred[h * HIDh + c];
  }
  __syncthreads();
  const int n = blockIdx.x * 4 + wv;
  const unsigned short* xp = x2 + (long)(bc * Nn + n) * HIDh * Mm + lane * 4;
  float red[NHh][4] = {};
#pragma unroll
  for (int c = 0; c < HIDh; c++) {
    const ushort4 xv = *(const ushort4*)&xp[c * Mm];
    const float Ac = wA[c], Bc = wB[c];
    float sw[4];
    sw[0] = swish_(fmaf(bfup(xv.x), Ac, Bc));
    sw[1] = swish_(fmaf(bfup(xv.y), Ac, Bc));
    sw[2] = swish_(fmaf(bfup(xv.z), Ac, Bc));
    sw[3] = swish_(fmaf(bfup(xv.w), Ac, Bc));
#pragma unroll
    for (int h = 0; h < NHh; h++) {
      const float w = wrs[c][h];
      red[h][0] = fmaf(w, sw[0], red[h][0]);
      red[h][1] = fmaf(w, sw[1], red[h][1]);
      red[h][2] = fmaf(w, sw[2], red[h][2]);
      red[h][3] = fmaf(w, sw[3], red[h][3]);
    }
  }
  float s3 = 0.f, q3 = 0.f;
#pragma unroll
  for (int h = 0; h < NHh; h++) {
    ushort4 st;
    st.x = f2bf(red[h][0]); st.y = f2bf(red[h][1]);
    st.z = f2bf(red[h][2]); st.w = f2bf(red[h][3]);
    *(ushort4*)&a2[(((long)b * NHh + h) * Nn + n) * Mm + lane * 4] = st;
#pragma unroll
    for (int mi = 0; mi < 4; mi++) {
      s3 += red[h][mi]; q3 = fmaf(red[h][mi], red[h][mi], q3);
    }
  }
  s3 = wave_sum(s3); q3 = wave_sum(q3);
  if (lane == 0) { red2[0][wv] = s3; red2[1][wv] = q3; }
  __syncthreads();
  if (tid < 2) {
    float t = red2[tid][0] + red2[tid][1] + red2[tid][2] + red2[tid][3];
    partial3[((long)b * 256 + blockIdx.x) * 2 + tid] = t;
  }
}

// ------------- finalize gn3 stats: reduce partial3[b][256][2] -> stats3[b][2] -------
__launch_bounds__(256)
__global__ void finalize_stats3(const float* __restrict__ partial3, float* __restrict__ stats3)
{
  __shared__ float red2[2][4];
  const int b = blockIdx.x, tid = threadIdx.x;
  const int lane = tid & 63, wv = tid >> 6;
  float s = partial3[((long)b * 256 + tid) * 2];
  float q = partial3[((long)b * 256 + tid) * 2 + 1];
  s = wave_sum(s); q = wave_sum(q);
  if (lane == 0) { red2[0][wv] = s; red2[1][wv] = q; }
  __syncthreads();
  if (tid < 2)
    stats3[b * 2 + tid] = red2[tid][0] + red2[tid][1] + red2[tid][2] + red2[tid][3];
}

// ------------- pv_out: gn3 (folded) + PV -> oT[b,c,n] (coalesced) -------------
__launch_bounds__(256)
__global__ void pv_out(const unsigned short* __restrict__ a2, const float* __restrict__ vb,
                       const float* __restrict__ sv, const float* __restrict__ stats3,
                       const float* __restrict__ g3, const float* __restrict__ b3,
                       float* __restrict__ o)
{
  __shared__ __align__(16) float As[16 * 260];
  __shared__ __align__(16) float Vs[Mm * HDd];
  const int b = blockIdx.z, h = blockIdx.y, n0 = blockIdx.x * 256;
  const int tid = threadIdx.x;
  const float* vp = vb + ((long)b * NHh + h) * Mm * HDd;
#pragma unroll
  for (int u = 0; u < 8; u++) {
    const int f = tid + u * 256;
    ((float4*)Vs)[f] = ((const float4*)vp)[f];
  }
  const unsigned short* ap = a2 + (((long)b * NHh + h) * Nn + n0) * Mm;
  const int tx = tid & 63, ty = tid >> 6;
  float acc[4][8] = {};
  for (int k0 = 0; k0 < Mm; k0 += 16) {
    __syncthreads();
#pragma unroll
    for (int u = 0; u < 2; u++) {
      const int s = tid + u * 256;
      const int row = s >> 1, half = (s & 1) * 8;
      const uint4 pk = *(const uint4*)(ap + (long)row * Mm + k0 + half);
      As[(half + 0) * 260 + row] = bflo(pk.x);
      As[(half + 1) * 260 + row] = bfhi(pk.x);
      As[(half + 2) * 260 + row] = bflo(pk.y);
      As[(half + 3) * 260 + row] = bfhi(pk.y);
      As[(half + 4) * 260 + row] = bflo(pk.z);
      As[(half + 5) * 260 + row] = bfhi(pk.z);
      As[(half + 6) * 260 + row] = bflo(pk.w);
      As[(half + 7) * 260 + row] = bfhi(pk.w);
    }
    __syncthreads();
#pragma unroll
    for (int k = 0; k < 16; k++) {
      const float4 a4 = *(const float4*)&As[k * 260 + tx * 4];
      const float4 w0 = *(const float4*)&Vs[(k0 + k) * HDd + ty * 8];
      const float4 w1 = *(const float4*)&Vs[(k0 + k) * HDd + ty * 8 + 4];
      const float av[4] = {a4.x, a4.y, a4.z, a4.w};
      const float vv[8] = {w0.x, w0.y, w0.z, w0.w, w1.x, w1.y, w1.z, w1.w};
#pragma unroll
      for (int u = 0; u < 4; u++)
#pragma unroll
        for (int v = 0; v < 8; v++)
          acc[u][v] = fmaf(av[u], vv[v], acc[u][v]);
    }
  }
  const float cnt = (float)(NHh * NMs);
  const float mu = stats3[b * 2] / cnt;
  const float var = stats3[b * 2 + 1] / cnt - mu * mu;
  const float r3 = rsqrtf(var + EPSf);
  const float alpha = r3 * g3[h];
  const float beta = b3[h] - mu * alpha;
  float svv[8];
#pragma unroll
  for (int v = 0; v < 8; v++) svv[v] = sv[((long)b * NHh + h) * HDd + ty * 8 + v];
#pragma unroll
  for (int v = 0; v < 8; v++) {
    const int c = h * HDd + ty * 8 + v;
    const float bv = beta * svv[v];
    float4 r4 = make_float4(fmaf(alpha, acc[0][v], bv), fmaf(alpha, acc[1][v], bv),
                            fmaf(alpha, acc[2][v], bv), fmaf(alpha, acc[3][v], bv));
    *(float4*)&o[((long)b * Cc + c) * Nn + n0 + tx * 4] = r4;
  }
}

extern "C" void kernel_launch(void* const* d_in, const int* in_sizes, int n_in,
                              void* d_out, int out_size, void* d_ws, size_t ws_size,
                              hipStream_t stream) {
  const float* q    = (const float*)d_in[0];
  const float* kv   = (const float*)d_in[1];
  const float* Wq   = (const float*)d_in[2];
  const float* Wkv  = (const float*)d_in[3];
  const float* Wp   = (const float*)d_in[4];
  const float* bp   = (const float*)d_in[5];
  const float* rpb  = (const float*)d_in[6];
  const float* Wexp = (const float*)d_in[7];
  const float* g1   = (const float*)d_in[8];
  const float* b1   = (const float*)d_in[9];
  const float* Wdw  = (const float*)d_in[10];
  const float* g2   = (const float*)d_in[11];
  const float* b2   = (const float*)d_in[12];
  const float* Wred = (const float*)d_in[13];
  const float* g3   = (const float*)d_in[14];
  const float* b3   = (const float*)d_in[15];
  float* out = (float*)d_out;

  float* ws = (float*)d_ws;
  size_t off = 0;
  auto alloc = [&](size_t n) { float* p = ws + off; off += n; return p; };
  float* attnf   = alloc((size_t)Bb * NHh * NMs / 2);      // 67.1 MB (bf16)
  float* a2f     = alloc((size_t)Bb * NHh * NMs / 2);      // 67.1 MB (bf16)
  float* big     = alloc((size_t)CHUNK * HIDh * NMs / 2);  // 100.7 MB: qhT -> x2 -> oT
  float* kbuf    = alloc((size_t)Bb * NHh * Mm * HDd);     // 4.2 MB
  float* vbuf    = alloc((size_t)Bb * NHh * Mm * HDd);     // 4.2 MB
  float* sv      = alloc((size_t)Bb * NHh * HDd);
  float* G       = alloc((size_t)Bb * 36 * STP);           // line-spread
  float* stats2c = alloc((size_t)Bb * HIDh * STP);         // line-spread
  float* stats3  = alloc(Bb * 2);
  float* partial3= alloc((size_t)Bb * 256 * 2);            // fully overwritten, no memset
  unsigned short* attn = (unsigned short*)attnf;
  unsigned short* a2 = (unsigned short*)a2f;
  float* qhT = big;                           // dead after attn_softmax
  unsigned short* x2 = (unsigned short*)big;  // alive during DLA chunk loop
  float* oT = big;                            // alive after last pass C

  // zero only the atomic-accumulated buffers (G | stats2c are contiguous)
  hipMemsetAsync(G, 0, (size_t)(Bb * 36 * STP + Bb * HIDh * STP) * sizeof(float), stream);

  gemm_tn<0><<<dim3(Nn / 64, Cc / 64, Bb), 256, 0, stream>>>(
      q, Wq, nullptr, qhT, nullptr, Cc, (long)Cc * Nn, Nn, 1);
  gemm_tn<1><<<dim3(Mm / 64, 512 / 64, Bb), 256, 0, stream>>>(
      kv, Wkv, nullptr, kbuf, vbuf, Cc, (long)Cc * Mm, Mm, 1);
  compute_sv<<<dim3(Bb * NHh), 256, 0, stream>>>(vbuf, sv);
  attn_softmax<<<dim3(Nn / 32, NHh, Bb), 256, 0, stream>>>(qhT, kbuf, rpb, attn);
  gram_stats<<<dim3(NMs / 2048, Bb), 256, 0, stream>>>(attn, G);

  for (int b0 = 0; b0 < Bb; b0 += CHUNK) {
    dla_pass_b<<<dim3(Nn / TTB, CHUNK), 768, 0, stream>>>(
        attn, Wexp, g1, b1, G, Wdw, x2, stats2c, b0);
    dla_pass_c<<<dim3(Nn / 4, CHUNK), 256, 0, stream>>>(
        x2, g2, b2, stats2c, Wred, a2, partial3, b0);
  }
  finalize_stats3<<<dim3(Bb), 256, 0, stream>>>(partial3, stats3);

  pv_out<<<dim3(Nn / 256, NHh, Bb), 256, 0, stream>>>(a2, vbuf, sv, stats3, g3, b3, oT);
  gemm_tn<2><<<dim3(Nn / 64, Cc / 64, Bb), 256, 0, stream>>>(
      oT, Wp, bp, out, nullptr, Cc, (long)Cc * Nn, Nn, 1);
}

// Round 13
// 597.602 us; speedup vs baseline: 1.2690x; 1.2690x over previous
//
#include <hip/hip_runtime.h>
#include <math.h>

#define Bb 16
#define Cc 256
#define Nn 1024
#define Mm 256
#define NHh 8
#define HDd 32
#define HIDh 24
#define NMs (Nn*Mm)
#define TTB 16
#define CHUNK 8
#define EPSf 1e-5f
#define SCALEf 0.17677669529663687f   // 1/sqrt(32)
#define STP 32   // stats padding stride (floats) = 128B cacheline

__device__ __forceinline__ float wave_sum(float v){
#pragma unroll
  for (int off=32; off; off>>=1) v += __shfl_xor(v, off, 64);
  return v;
}
__device__ __forceinline__ float wave_max(float v){
#pragma unroll
  for (int off=32; off; off>>=1) v = fmaxf(v, __shfl_xor(v, off, 64));
  return v;
}
__device__ __forceinline__ float swish_(float x){ return x / (1.f + __expf(-x)); }
__device__ __forceinline__ unsigned short f2bf(float f){
  unsigned u = __float_as_uint(f);
  u += 0x7fffu + ((u >> 16) & 1u);          // round-to-nearest-even
  return (unsigned short)(u >> 16);
}
__device__ __forceinline__ float bfup(unsigned short s){ return __uint_as_float(((unsigned)s) << 16); }
__device__ __forceinline__ float bflo(unsigned u){ return __uint_as_float(u << 16); }
__device__ __forceinline__ float bfhi(unsigned u){ return __uint_as_float(u & 0xffff0000u); }
__device__ __forceinline__ unsigned pk2bf(float lo, float hi){
  return (unsigned)f2bf(lo) | ((unsigned)f2bf(hi) << 16);
}

// ------------- GEMM: out[b,i,j] = sum_k A[b,k,i]*W[j,k] (+bias) -------------
template<int MODE>
__launch_bounds__(256)
__global__ void gemm_tn(const float* __restrict__ A, const float* __restrict__ W,
                        const float* __restrict__ bias, float* __restrict__ O1,
                        float* __restrict__ O2, int Kdim, long sAb, int sAk, int sAi)
{
  __shared__ __align__(16) float As[16][68];
  __shared__ __align__(16) float Ws[16][68];
  const int b  = blockIdx.z;
  const int i0 = blockIdx.x * 64;
  const int j0 = blockIdx.y * 64;
  const int tid = threadIdx.x;
  const int tx = tid & 15, ty = tid >> 4;
  const float* Ab = A + (long)b * sAb;
  float acc[4][4] = {};
  for (int k0 = 0; k0 < Kdim; k0 += 16) {
#pragma unroll
    for (int t = 0; t < 4; t++) {
      int idx = tid + t * 256;
      int kk, ii;
      if (sAi == 1) { kk = idx >> 6; ii = idx & 63; }
      else          { ii = idx >> 4; kk = idx & 15; }
      As[kk][ii] = Ab[(long)(k0 + kk) * sAk + (long)(i0 + ii) * sAi];
    }
#pragma unroll
    for (int t = 0; t < 4; t++) {
      int idx = tid + t * 256;
      int jj = idx & 63, kk = idx >> 6;
      Ws[kk][jj] = W[(long)(j0 + jj) * Kdim + (k0 + kk)];
    }
    __syncthreads();
#pragma unroll
    for (int kk = 0; kk < 16; kk++) {
      const float4 av = *(const float4*)&As[kk][tx * 4];
      const float4 wv = *(const float4*)&Ws[kk][ty * 4];
      const float a4[4] = {av.x, av.y, av.z, av.w};
      const float w4[4] = {wv.x, wv.y, wv.z, wv.w};
#pragma unroll
      for (int u = 0; u < 4; u++)
#pragma unroll
        for (int v = 0; v < 4; v++)
          acc[u][v] = fmaf(a4[u], w4[v], acc[u][v]);
    }
    __syncthreads();
  }
#pragma unroll
  for (int v = 0; v < 4; v++) {
    const int j = j0 + ty * 4 + v;
    if (MODE == 0) {
      const int h = j >> 5, d = j & 31;
      float4 r4 = make_float4(acc[0][v], acc[1][v], acc[2][v], acc[3][v]);
      *(float4*)&O1[(((long)b * NHh + h) * HDd + d) * Nn + i0 + tx * 4] = r4;
    } else if (MODE == 2) {
      const float bb = bias[j];
      float4 r4 = make_float4(acc[0][v] + bb, acc[1][v] + bb, acc[2][v] + bb, acc[3][v] + bb);
      *(float4*)&O1[((long)b * Cc + j) * Nn + i0 + tx * 4] = r4;
    } else {
      const int two = j >> 8, jj = j & 255;
      const int h = jj >> 5, d = jj & 31;
      float* p = two ? O2 : O1;
#pragma unroll
      for (int u = 0; u < 4; u++)
        p[(((long)b * NHh + h) * Mm + (i0 + tx * 4 + u)) * HDd + d] = acc[u][v];
    }
  }
}

// ------------- sv[b,h,d] = sum_m v[b,h,m,d] -------------
__launch_bounds__(256)
__global__ void compute_sv(const float* __restrict__ vb, float* __restrict__ sv)
{
  __shared__ float red[256];
  const int bh = blockIdx.x, tid = threadIdx.x;
  const int d = tid & 31, ch = tid >> 5;
  const float* vp = vb + (long)bh * Mm * HDd;
  float s = 0.f;
  for (int m = ch; m < Mm; m += 8) s += vp[m * HDd + d];
  red[tid] = s;
  __syncthreads();
  if (tid < 32) {
    float t = 0.f;
#pragma unroll
    for (int cc = 0; cc < 8; cc++) t += red[cc * 32 + tid];
    sv[(long)bh * HDd + tid] = t;
  }
}

// ------------- scores + softmax -> attn (bf16) -------------
__launch_bounds__(256)
__global__ void attn_softmax(const float* __restrict__ qhT, const float* __restrict__ kb,
                             const float* __restrict__ rpb, unsigned short* __restrict__ attn)
{
  __shared__ __align__(16) float Ks[Mm][36];
  __shared__ __align__(16) float qs[32][36];
  const int b = blockIdx.z, h = blockIdx.y, n0 = blockIdx.x * 32;
  const int tid = threadIdx.x;
  const float* kp = kb + ((long)b * NHh + h) * Mm * HDd;
#pragma unroll
  for (int u = 0; u < 8; u++) {
    const int f = tid + u * 256;
    const int m = f >> 3, d = (f & 7) * 4;
    *(float4*)&Ks[m][d] = *(const float4*)&kp[m * HDd + d];
  }
  const float* qp = qhT + ((long)b * NHh + h) * HDd * Nn;
#pragma unroll
  for (int u = 0; u < 4; u++) {
    const int idx = tid + u * 256;
    const int nn = idx & 31, dd = idx >> 5;
    qs[nn][dd] = qp[(long)dd * Nn + n0 + nn];
  }
  __syncthreads();
  const int lane = tid & 63, w = tid >> 6;
  const int r0 = w * 8;
  float s[8][4] = {};
#pragma unroll
  for (int dq = 0; dq < 8; dq++) {
    float4 k4[4];
#pragma unroll
    for (int j = 0; j < 4; j++) k4[j] = *(const float4*)&Ks[lane + j * 64][dq * 4];
#pragma unroll
    for (int r = 0; r < 8; r++) {
      const float4 q4 = *(const float4*)&qs[r0 + r][dq * 4];
#pragma unroll
      for (int j = 0; j < 4; j++) {
        s[r][j] = fmaf(q4.x, k4[j].x, s[r][j]);
        s[r][j] = fmaf(q4.y, k4[j].y, s[r][j]);
        s[r][j] = fmaf(q4.z, k4[j].z, s[r][j]);
        s[r][j] = fmaf(q4.w, k4[j].w, s[r][j]);
      }
    }
  }
#pragma unroll
  for (int r = 0; r < 8; r++) {
    const int n = n0 + r0 + r;
    const float* rp = rpb + (long)n * Mm;
    float sc[4];
#pragma unroll
    for (int j = 0; j < 4; j++) sc[j] = fmaf(s[r][j], SCALEf, rp[lane + j * 64]);
    float mx = fmaxf(fmaxf(sc[0], sc[1]), fmaxf(sc[2], sc[3]));
    mx = wave_max(mx);
    float e[4], sum = 0.f;
#pragma unroll
    for (int j = 0; j < 4; j++) { e[j] = __expf(sc[j] - mx); sum += e[j]; }
    sum = wave_sum(sum);
    const float inv = 1.f / sum;
    unsigned short* ap = attn + (((long)b * NHh + h) * Nn + n) * Mm;
#pragma unroll
    for (int j = 0; j < 4; j++) ap[lane + j * 64] = f2bf(e[j] * inv);
  }
}

// ------------- Gram matrix G[b][36*STP] (line-spread atomics) -------------
__launch_bounds__(256)
__global__ void gram_stats(const unsigned short* __restrict__ attn, float* __restrict__ G)
{
  __shared__ float red[36][4];
  const int b = blockIdx.y, tid = threadIdx.x;
  const unsigned short* ap = attn + (long)b * NHh * NMs + (long)blockIdx.x * 2048 + tid * 8;
  float a[8][8];
#pragma unroll
  for (int h = 0; h < 8; h++) {
    const uint4 v = *(const uint4*)&ap[(long)h * NMs];
    a[h][0] = bflo(v.x); a[h][1] = bfhi(v.x); a[h][2] = bflo(v.y); a[h][3] = bfhi(v.y);
    a[h][4] = bflo(v.z); a[h][5] = bfhi(v.z); a[h][6] = bflo(v.w); a[h][7] = bfhi(v.w);
  }
  float g[36];
  int t = 0;
#pragma unroll
  for (int i = 0; i < 8; i++)
#pragma unroll
    for (int j = i; j < 8; j++, t++) {
      float s = 0.f;
#pragma unroll
      for (int m = 0; m < 8; m++) s = fmaf(a[i][m], a[j][m], s);
      g[t] = s;
    }
  const int lane = tid & 63, wid = tid >> 6;
#pragma unroll
  for (int t2 = 0; t2 < 36; t2++) {
    const float s = wave_sum(g[t2]);
    if (lane == 0) red[t2][wid] = s;
  }
  __syncthreads();
  if (tid < 36)
    atomicAdd(&G[((long)b * 36 + tid) * STP],
              red[tid][0] + red[tid][1] + red[tid][2] + red[tid][3]);
}

// ------------- pass B: expand+gn1(from G)+swish -> conv3x3 -> x2(bf16) + gn2 stats ----
// R11 exact: one-shot staging of all 18 halo rows (72 KB LDS), ONE barrier,
// TTB=16 / 512 blocks — the measured traffic-clean geometry (FETCH ~ unique).
__launch_bounds__(768)
__global__ void dla_pass_b(const unsigned short* __restrict__ attn,
                           const float* __restrict__ Wexp,
                           const float* __restrict__ g1, const float* __restrict__ b1,
                           const float* __restrict__ G, const float* __restrict__ Wdw,
                           unsigned short* __restrict__ x2, float* __restrict__ stats2c, int b0)
{
  __shared__ __align__(16) unsigned short sl[TTB + 2][NHh][Mm];   // 18 x 4 KB = 72 KB
  const int tid = threadIdx.x;
  const int wv = tid >> 6, lane = tid & 63;
  const int bc = blockIdx.y, b = b0 + bc;
  const int n0 = blockIdx.x * TTB;
  const int c0 = wv * 2;
  const int g = c0 >> 3;
  // gn1 stats from Gram matrix (mean exact: softmax rows sum to 1)
  float mu, rs;
  {
    const float* Gb = G + (long)b * 36 * STP;
    float sum = 0.f, sumsq = 0.f;
    for (int c = g * 8; c < g * 8 + 8; c++) {
      float w[8];
#pragma unroll
      for (int h = 0; h < 8; h++) w[h] = Wexp[c * 8 + h];
      float wsu = 0.f;
#pragma unroll
      for (int h = 0; h < 8; h++) wsu += w[h];
      sum += wsu;
      float s2 = 0.f;
      int t = 0;
#pragma unroll
      for (int i = 0; i < 8; i++)
#pragma unroll
        for (int j = i; j < 8; j++, t++) {
          const float f = (i == j) ? 1.f : 2.f;
          s2 = fmaf(f * w[i] * w[j], Gb[t * STP], s2);
        }
      sumsq += s2;
    }
    const float cnt = 8.f * NMs;
    mu = sum * ((float)Nn / cnt);
    const float var = sumsq / cnt - mu * mu;
    rs = rsqrtf(var + EPSf);
  }
  float we[2][8], B1f[2], wd[2][9];
#pragma unroll
  for (int j = 0; j < 2; j++) {
    const int c = c0 + j;
    const float A1 = rs * g1[c];
    B1f[j] = b1[c] - mu * A1;
#pragma unroll
    for (int h = 0; h < NHh; h++) we[j][h] = Wexp[c * NHh + h] * A1;
#pragma unroll
    for (int k = 0; k < 9; k++) wd[j][k] = Wdw[c * 9 + k];
  }
  // stage all 18 rows: 18*8*32 = 4608 uint4s, 6 per thread, coalesced
  const unsigned short* ab = attn + (long)b * NHh * NMs;
#pragma unroll
  for (int k = 0; k < 6; k++) {
    const int f = tid + k * 768;
    const int row = f >> 8;
    const int rem = f & 255;
    const int h = rem >> 5, seg = rem & 31;
    const int nn = n0 - 1 + row;
    uint4 v = make_uint4(0u, 0u, 0u, 0u);
    if (nn >= 0 && nn < Nn)
      v = *(const uint4*)&ab[(long)h * NMs + (long)nn * Mm + seg * 8];
    *(uint4*)&sl[row][h][seg * 8] = v;
  }
  __syncthreads();   // the only barrier: all rows staged
  float s1[2][4] = {}, s2v[2][4] = {};
  float sm[2] = {}, sq[2] = {};
  for (int r = -1; r <= TTB; r++) {
    const int nn = n0 + r;
    const bool rowv = (nn >= 0 && nn < Nn);
    float af[8][4];
#pragma unroll
    for (int h = 0; h < NHh; h++) {
      const ushort4 v = *(const ushort4*)&sl[r + 1][h][lane * 4];
      af[h][0] = bfup(v.x); af[h][1] = bfup(v.y);
      af[h][2] = bfup(v.z); af[h][3] = bfup(v.w);
    }
#pragma unroll
    for (int j = 0; j < 2; j++) {
      float x1[4];
      if (rowv) {
#pragma unroll
        for (int mi = 0; mi < 4; mi++) {
          float x = B1f[j];
#pragma unroll
          for (int h = 0; h < NHh; h++) x = fmaf(we[j][h], af[h][mi], x);
          x1[mi] = swish_(x);
        }
      } else {
#pragma unroll
        for (int mi = 0; mi < 4; mi++) x1[mi] = 0.f;
      }
      float xl = __shfl_up(x1[3], 1);
      float xr = __shfl_down(x1[0], 1);
      if (lane == 0) xl = 0.f;
      if (lane == 63) xr = 0.f;
      const float L[4]  = {xl, x1[0], x1[1], x1[2]};
      const float Ce[4] = {x1[0], x1[1], x1[2], x1[3]};
      const float R[4]  = {x1[1], x1[2], x1[3], xr};
      float y[4];
#pragma unroll
      for (int mi = 0; mi < 4; mi++) {
        const float u0 = wd[j][0]*L[mi] + wd[j][1]*Ce[mi] + wd[j][2]*R[mi];
        const float u1 = wd[j][3]*L[mi] + wd[j][4]*Ce[mi] + wd[j][5]*R[mi];
        const float u2 = wd[j][6]*L[mi] + wd[j][7]*Ce[mi] + wd[j][8]*R[mi];
        y[mi] = s2v[j][mi] + u2;
        s2v[j][mi] = s1[j][mi] + u1;
        s1[j][mi] = u0;
      }
      if (r >= 1) {
#pragma unroll
        for (int mi = 0; mi < 4; mi++) { sm[j] += y[mi]; sq[j] = fmaf(y[mi], y[mi], sq[j]); }
        ushort4 st;
        st.x = f2bf(y[0]); st.y = f2bf(y[1]); st.z = f2bf(y[2]); st.w = f2bf(y[3]);
        const int nw = n0 + r - 1;
        *(ushort4*)&x2[((long)(bc * Nn + nw) * HIDh + (c0 + j)) * Mm + lane * 4] = st;
      }
    }
  }
#pragma unroll
  for (int j = 0; j < 2; j++) {
    const float vs = wave_sum(sm[j]);
    const float vq = wave_sum(sq[j]);
    if (lane == 0) {
      atomicAdd(&stats2c[((long)b * HIDh + c0 + j) * STP], vs);
      atomicAdd(&stats2c[((long)b * HIDh + c0 + j) * STP + 1], vq);
    }
  }
}

// ------------- pass C: gn2+swish + 1x1 reduce -> a2(bf16) + partial gn3 stats -------
// Wave handles 2 rows: lane = (row-half, 32 m-strips of 8). All x2 loads and
// a2 stores are 16 B/lane. Block covers 8 rows; grid (Nn/8, CHUNK).
__launch_bounds__(256)
__global__ void dla_pass_c(const unsigned short* __restrict__ x2, const float* __restrict__ g2,
                           const float* __restrict__ b2, const float* __restrict__ stats2c,
                           const float* __restrict__ Wred, unsigned short* __restrict__ a2,
                           float* __restrict__ partial3, int b0)
{
  __shared__ float wA[HIDh], wB[HIDh], wrs[HIDh][NHh];
  __shared__ float red2[2][4];
  const int tid = threadIdx.x;
  const int wv = tid >> 6, lane = tid & 63;
  const int bc = blockIdx.y, b = b0 + bc;
  if (tid < HIDh) {
    const int c = tid, g = c >> 3;
    float s = 0.f, q = 0.f;
#pragma unroll
    for (int cc = 0; cc < 8; cc++) {
      s += stats2c[((long)b * HIDh + g * 8 + cc) * STP];
      q += stats2c[((long)b * HIDh + g * 8 + cc) * STP + 1];
    }
    const float cnt = 8.f * NMs;
    const float mu = s / cnt;
    const float var = q / cnt - mu * mu;
    const float A2 = rsqrtf(var + EPSf) * g2[c];
    wA[c] = A2; wB[c] = b2[c] - mu * A2;
  }
  if (tid < HIDh * NHh) {
    const int c = tid >> 3, h = tid & 7;
    wrs[c][h] = Wred[h * HIDh + c];
  }
  __syncthreads();
  const int rsel = lane >> 5, ms = lane & 31;
  const int n = blockIdx.x * 8 + wv * 2 + rsel;
  const unsigned short* xp = x2 + (long)(bc * Nn + n) * HIDh * Mm + ms * 8;
  float red[NHh][8] = {};
#pragma unroll
  for (int c = 0; c < HIDh; c++) {
    const uint4 xv = *(const uint4*)&xp[c * Mm];
    const float Ac = wA[c], Bc = wB[c];
    float sw[8];
    sw[0] = swish_(fmaf(bflo(xv.x), Ac, Bc));
    sw[1] = swish_(fmaf(bfhi(xv.x), Ac, Bc));
    sw[2] = swish_(fmaf(bflo(xv.y), Ac, Bc));
    sw[3] = swish_(fmaf(bfhi(xv.y), Ac, Bc));
    sw[4] = swish_(fmaf(bflo(xv.z), Ac, Bc));
    sw[5] = swish_(fmaf(bfhi(xv.z), Ac, Bc));
    sw[6] = swish_(fmaf(bflo(xv.w), Ac, Bc));
    sw[7] = swish_(fmaf(bfhi(xv.w), Ac, Bc));
#pragma unroll
    for (int h = 0; h < NHh; h++) {
      const float w = wrs[c][h];
#pragma unroll
      for (int mi = 0; mi < 8; mi++) red[h][mi] = fmaf(w, sw[mi], red[h][mi]);
    }
  }
  float s3 = 0.f, q3 = 0.f;
#pragma unroll
  for (int h = 0; h < NHh; h++) {
    uint4 st;
    st.x = pk2bf(red[h][0], red[h][1]);
    st.y = pk2bf(red[h][2], red[h][3]);
    st.z = pk2bf(red[h][4], red[h][5]);
    st.w = pk2bf(red[h][6], red[h][7]);
    *(uint4*)&a2[(((long)b * NHh + h) * Nn + n) * Mm + ms * 8] = st;
#pragma unroll
    for (int mi = 0; mi < 8; mi++) {
      s3 += red[h][mi]; q3 = fmaf(red[h][mi], red[h][mi], q3);
    }
  }
  s3 = wave_sum(s3); q3 = wave_sum(q3);
  if (lane == 0) { red2[0][wv] = s3; red2[1][wv] = q3; }
  __syncthreads();
  if (tid < 2) {
    float t = red2[tid][0] + red2[tid][1] + red2[tid][2] + red2[tid][3];
    partial3[((long)b * 128 + blockIdx.x) * 2 + tid] = t;
  }
}

// ------------- finalize gn3 stats: reduce partial3[b][128][2] -> stats3[b][2] -------
__launch_bounds__(128)
__global__ void finalize_stats3(const float* __restrict__ partial3, float* __restrict__ stats3)
{
  __shared__ float red2[2][2];
  const int b = blockIdx.x, tid = threadIdx.x;
  const int lane = tid & 63, wv = tid >> 6;
  float s = partial3[((long)b * 128 + tid) * 2];
  float q = partial3[((long)b * 128 + tid) * 2 + 1];
  s = wave_sum(s); q = wave_sum(q);
  if (lane == 0) { red2[0][wv] = s; red2[1][wv] = q; }
  __syncthreads();
  if (tid < 2)
    stats3[b * 2 + tid] = red2[tid][0] + red2[tid][1];
}

// ------------- pv_out: gn3 (folded) + PV -> oT[b,c,n] (coalesced) -------------
__launch_bounds__(256)
__global__ void pv_out(const unsigned short* __restrict__ a2, const float* __restrict__ vb,
                       const float* __restrict__ sv, const float* __restrict__ stats3,
                       const float* __restrict__ g3, const float* __restrict__ b3,
                       float* __restrict__ o)
{
  __shared__ __align__(16) float As[16 * 260];
  __shared__ __align__(16) float Vs[Mm * HDd];
  const int b = blockIdx.z, h = blockIdx.y, n0 = blockIdx.x * 256;
  const int tid = threadIdx.x;
  const float* vp = vb + ((long)b * NHh + h) * Mm * HDd;
#pragma unroll
  for (int u = 0; u < 8; u++) {
    const int f = tid + u * 256;
    ((float4*)Vs)[f] = ((const float4*)vp)[f];
  }
  const unsigned short* ap = a2 + (((long)b * NHh + h) * Nn + n0) * Mm;
  const int tx = tid & 63, ty = tid >> 6;
  float acc[4][8] = {};
  for (int k0 = 0; k0 < Mm; k0 += 16) {
    __syncthreads();
#pragma unroll
    for (int u = 0; u < 2; u++) {
      const int s = tid + u * 256;
      const int row = s >> 1, half = (s & 1) * 8;
      const uint4 pk = *(const uint4*)(ap + (long)row * Mm + k0 + half);
      As[(half + 0) * 260 + row] = bflo(pk.x);
      As[(half + 1) * 260 + row] = bfhi(pk.x);
      As[(half + 2) * 260 + row] = bflo(pk.y);
      As[(half + 3) * 260 + row] = bfhi(pk.y);
      As[(half + 4) * 260 + row] = bflo(pk.z);
      As[(half + 5) * 260 + row] = bfhi(pk.z);
      As[(half + 6) * 260 + row] = bflo(pk.w);
      As[(half + 7) * 260 + row] = bfhi(pk.w);
    }
    __syncthreads();
#pragma unroll
    for (int k = 0; k < 16; k++) {
      const float4 a4 = *(const float4*)&As[k * 260 + tx * 4];
      const float4 w0 = *(const float4*)&Vs[(k0 + k) * HDd + ty * 8];
      const float4 w1 = *(const float4*)&Vs[(k0 + k) * HDd + ty * 8 + 4];
      const float av[4] = {a4.x, a4.y, a4.z, a4.w};
      const float vv[8] = {w0.x, w0.y, w0.z, w0.w, w1.x, w1.y, w1.z, w1.w};
#pragma unroll
      for (int u = 0; u < 4; u++)
#pragma unroll
        for (int v = 0; v < 8; v++)
          acc[u][v] = fmaf(av[u], vv[v], acc[u][v]);
    }
  }
  const float cnt = (float)(NHh * NMs);
  const float mu = stats3[b * 2] / cnt;
  const float var = stats3[b * 2 + 1] / cnt - mu * mu;
  const float r3 = rsqrtf(var + EPSf);
  const float alpha = r3 * g3[h];
  const float beta = b3[h] - mu * alpha;
  float svv[8];
#pragma unroll
  for (int v = 0; v < 8; v++) svv[v] = sv[((long)b * NHh + h) * HDd + ty * 8 + v];
#pragma unroll
  for (int v = 0; v < 8; v++) {
    const int c = h * HDd + ty * 8 + v;
    const float bv = beta * svv[v];
    float4 r4 = make_float4(fmaf(alpha, acc[0][v], bv), fmaf(alpha, acc[1][v], bv),
                            fmaf(alpha, acc[2][v], bv), fmaf(alpha, acc[3][v], bv));
    *(float4*)&o[((long)b * Cc + c) * Nn + n0 + tx * 4] = r4;
  }
}

extern "C" void kernel_launch(void* const* d_in, const int* in_sizes, int n_in,
                              void* d_out, int out_size, void* d_ws, size_t ws_size,
                              hipStream_t stream) {
  const float* q    = (const float*)d_in[0];
  const float* kv   = (const float*)d_in[1];
  const float* Wq   = (const float*)d_in[2];
  const float* Wkv  = (const float*)d_in[3];
  const float* Wp   = (const float*)d_in[4];
  const float* bp   = (const float*)d_in[5];
  const float* rpb  = (const float*)d_in[6];
  const float* Wexp = (const float*)d_in[7];
  const float* g1   = (const float*)d_in[8];
  const float* b1   = (const float*)d_in[9];
  const float* Wdw  = (const float*)d_in[10];
  const float* g2   = (const float*)d_in[11];
  const float* b2   = (const float*)d_in[12];
  const float* Wred = (const float*)d_in[13];
  const float* g3   = (const float*)d_in[14];
  const float* b3   = (const float*)d_in[15];
  float* out = (float*)d_out;

  float* ws = (float*)d_ws;
  size_t off = 0;
  auto alloc = [&](size_t n) { float* p = ws + off; off += n; return p; };
  float* attnf   = alloc((size_t)Bb * NHh * NMs / 2);      // 67.1 MB (bf16)
  float* a2f     = alloc((size_t)Bb * NHh * NMs / 2);      // 67.1 MB (bf16)
  float* big     = alloc((size_t)CHUNK * HIDh * NMs / 2);  // 100.7 MB: qhT -> x2 -> oT
  float* kbuf    = alloc((size_t)Bb * NHh * Mm * HDd);     // 4.2 MB
  float* vbuf    = alloc((size_t)Bb * NHh * Mm * HDd);     // 4.2 MB
  float* sv      = alloc((size_t)Bb * NHh * HDd);
  float* G       = alloc((size_t)Bb * 36 * STP);           // line-spread
  float* stats2c = alloc((size_t)Bb * HIDh * STP);         // line-spread
  float* stats3  = alloc(Bb * 2);
  float* partial3= alloc((size_t)Bb * 128 * 2);            // fully overwritten, no memset
  unsigned short* attn = (unsigned short*)attnf;
  unsigned short* a2 = (unsigned short*)a2f;
  float* qhT = big;                           // dead after attn_softmax
  unsigned short* x2 = (unsigned short*)big;  // alive during DLA chunk loop
  float* oT = big;                            // alive after last pass C

  // zero only the atomic-accumulated buffers (G | stats2c are contiguous)
  hipMemsetAsync(G, 0, (size_t)(Bb * 36 * STP + Bb * HIDh * STP) * sizeof(float), stream);

  gemm_tn<0><<<dim3(Nn / 64, Cc / 64, Bb), 256, 0, stream>>>(
      q, Wq, nullptr, qhT, nullptr, Cc, (long)Cc * Nn, Nn, 1);
  gemm_tn<1><<<dim3(Mm / 64, 512 / 64, Bb), 256, 0, stream>>>(
      kv, Wkv, nullptr, kbuf, vbuf, Cc, (long)Cc * Mm, Mm, 1);
  compute_sv<<<dim3(Bb * NHh), 256, 0, stream>>>(vbuf, sv);
  attn_softmax<<<dim3(Nn / 32, NHh, Bb), 256, 0, stream>>>(qhT, kbuf, rpb, attn);
  gram_stats<<<dim3(NMs / 2048, Bb), 256, 0, stream>>>(attn, G);

  for (int b0 = 0; b0 < Bb; b0 += CHUNK) {
    dla_pass_b<<<dim3(Nn / TTB, CHUNK), 768, 0, stream>>>(
        attn, Wexp, g1, b1, G, Wdw, x2, stats2c, b0);
    dla_pass_c<<<dim3(Nn / 8, CHUNK), 256, 0, stream>>>(
        x2, g2, b2, stats2c, Wred, a2, partial3, b0);
  }
  finalize_stats3<<<dim3(Bb), 128, 0, stream>>>(partial3, stats3);

  pv_out<<<dim3(Nn / 256, NHh, Bb), 256, 0, stream>>>(a2, vbuf, sv, stats3, g3, b3, oT);
  gemm_tn<2><<<dim3(Nn / 64, Cc / 64, Bb), 256, 0, stream>>>(
      oT, Wp, bp, out, nullptr, Cc, (long)Cc * Nn, Nn, 1);
}

// Round 14
// 564.451 us; speedup vs baseline: 1.3435x; 1.0587x over previous
//
#include <hip/hip_runtime.h>
#include <math.h>

#define Bb 16
#define Cc 256
#define Nn 1024
#define Mm 256
#define NHh 8
#define HDd 32
#define HIDh 24
#define NMs (Nn*Mm)
#define TTB 16
#define CHUNK 8
#define EPSf 1e-5f
#define SCALEf 0.17677669529663687f   // 1/sqrt(32)
#define STP 32   // stats padding stride (floats) = 128B cacheline

typedef float v2f __attribute__((ext_vector_type(2)));

__device__ __forceinline__ float wave_sum(float v){
#pragma unroll
  for (int off=32; off; off>>=1) v += __shfl_xor(v, off, 64);
  return v;
}
__device__ __forceinline__ float wave_max(float v){
#pragma unroll
  for (int off=32; off; off>>=1) v = fmaxf(v, __shfl_xor(v, off, 64));
  return v;
}
__device__ __forceinline__ float swish_(float x){ return x / (1.f + __expf(-x)); }
__device__ __forceinline__ v2f swish2(v2f x){
  v2f r;
  r.x = x.x / (1.f + __expf(-x.x));
  r.y = x.y / (1.f + __expf(-x.y));
  return r;
}
__device__ __forceinline__ unsigned short f2bf(float f){
  unsigned u = __float_as_uint(f);
  u += 0x7fffu + ((u >> 16) & 1u);          // round-to-nearest-even
  return (unsigned short)(u >> 16);
}
__device__ __forceinline__ float bfup(unsigned short s){ return __uint_as_float(((unsigned)s) << 16); }
__device__ __forceinline__ float bflo(unsigned u){ return __uint_as_float(u << 16); }
__device__ __forceinline__ float bfhi(unsigned u){ return __uint_as_float(u & 0xffff0000u); }
__device__ __forceinline__ unsigned pk2bf(float lo, float hi){
  return (unsigned)f2bf(lo) | ((unsigned)f2bf(hi) << 16);
}

// ------------- GEMM: out[b,i,j] = sum_k A[b,k,i]*W[j,k] (+bias) -------------
template<int MODE>
__launch_bounds__(256)
__global__ void gemm_tn(const float* __restrict__ A, const float* __restrict__ W,
                        const float* __restrict__ bias, float* __restrict__ O1,
                        float* __restrict__ O2, int Kdim, long sAb, int sAk, int sAi)
{
  __shared__ __align__(16) float As[16][68];
  __shared__ __align__(16) float Ws[16][68];
  const int b  = blockIdx.z;
  const int i0 = blockIdx.x * 64;
  const int j0 = blockIdx.y * 64;
  const int tid = threadIdx.x;
  const int tx = tid & 15, ty = tid >> 4;
  const float* Ab = A + (long)b * sAb;
  float acc[4][4] = {};
  for (int k0 = 0; k0 < Kdim; k0 += 16) {
#pragma unroll
    for (int t = 0; t < 4; t++) {
      int idx = tid + t * 256;
      int kk, ii;
      if (sAi == 1) { kk = idx >> 6; ii = idx & 63; }
      else          { ii = idx >> 4; kk = idx & 15; }
      As[kk][ii] = Ab[(long)(k0 + kk) * sAk + (long)(i0 + ii) * sAi];
    }
#pragma unroll
    for (int t = 0; t < 4; t++) {
      int idx = tid + t * 256;
      int jj = idx & 63, kk = idx >> 6;
      Ws[kk][jj] = W[(long)(j0 + jj) * Kdim + (k0 + kk)];
    }
    __syncthreads();
#pragma unroll
    for (int kk = 0; kk < 16; kk++) {
      const float4 av = *(const float4*)&As[kk][tx * 4];
      const float4 wv = *(const float4*)&Ws[kk][ty * 4];
      const float a4[4] = {av.x, av.y, av.z, av.w};
      const float w4[4] = {wv.x, wv.y, wv.z, wv.w};
#pragma unroll
      for (int u = 0; u < 4; u++)
#pragma unroll
        for (int v = 0; v < 4; v++)
          acc[u][v] = fmaf(a4[u], w4[v], acc[u][v]);
    }
    __syncthreads();
  }
#pragma unroll
  for (int v = 0; v < 4; v++) {
    const int j = j0 + ty * 4 + v;
    if (MODE == 0) {
      const int h = j >> 5, d = j & 31;
      float4 r4 = make_float4(acc[0][v], acc[1][v], acc[2][v], acc[3][v]);
      *(float4*)&O1[(((long)b * NHh + h) * HDd + d) * Nn + i0 + tx * 4] = r4;
    } else if (MODE == 2) {
      const float bb = bias[j];
      float4 r4 = make_float4(acc[0][v] + bb, acc[1][v] + bb, acc[2][v] + bb, acc[3][v] + bb);
      *(float4*)&O1[((long)b * Cc + j) * Nn + i0 + tx * 4] = r4;
    } else {
      const int two = j >> 8, jj = j & 255;
      const int h = jj >> 5, d = jj & 31;
      float* p = two ? O2 : O1;
#pragma unroll
      for (int u = 0; u < 4; u++)
        p[(((long)b * NHh + h) * Mm + (i0 + tx * 4 + u)) * HDd + d] = acc[u][v];
    }
  }
}

// ------------- sv[b,h,d] = sum_m v[b,h,m,d] -------------
__launch_bounds__(256)
__global__ void compute_sv(const float* __restrict__ vb, float* __restrict__ sv)
{
  __shared__ float red[256];
  const int bh = blockIdx.x, tid = threadIdx.x;
  const int d = tid & 31, ch = tid >> 5;
  const float* vp = vb + (long)bh * Mm * HDd;
  float s = 0.f;
  for (int m = ch; m < Mm; m += 8) s += vp[m * HDd + d];
  red[tid] = s;
  __syncthreads();
  if (tid < 32) {
    float t = 0.f;
#pragma unroll
    for (int cc = 0; cc < 8; cc++) t += red[cc * 32 + tid];
    sv[(long)bh * HDd + tid] = t;
  }
}

// ------------- scores + softmax -> attn (bf16) -------------
__launch_bounds__(256)
__global__ void attn_softmax(const float* __restrict__ qhT, const float* __restrict__ kb,
                             const float* __restrict__ rpb, unsigned short* __restrict__ attn)
{
  __shared__ __align__(16) float Ks[Mm][36];
  __shared__ __align__(16) float qs[32][36];
  const int b = blockIdx.z, h = blockIdx.y, n0 = blockIdx.x * 32;
  const int tid = threadIdx.x;
  const float* kp = kb + ((long)b * NHh + h) * Mm * HDd;
#pragma unroll
  for (int u = 0; u < 8; u++) {
    const int f = tid + u * 256;
    const int m = f >> 3, d = (f & 7) * 4;
    *(float4*)&Ks[m][d] = *(const float4*)&kp[m * HDd + d];
  }
  const float* qp = qhT + ((long)b * NHh + h) * HDd * Nn;
#pragma unroll
  for (int u = 0; u < 4; u++) {
    const int idx = tid + u * 256;
    const int nn = idx & 31, dd = idx >> 5;
    qs[nn][dd] = qp[(long)dd * Nn + n0 + nn];
  }
  __syncthreads();
  const int lane = tid & 63, w = tid >> 6;
  const int r0 = w * 8;
  float s[8][4] = {};
#pragma unroll
  for (int dq = 0; dq < 8; dq++) {
    float4 k4[4];
#pragma unroll
    for (int j = 0; j < 4; j++) k4[j] = *(const float4*)&Ks[lane + j * 64][dq * 4];
#pragma unroll
    for (int r = 0; r < 8; r++) {
      const float4 q4 = *(const float4*)&qs[r0 + r][dq * 4];
#pragma unroll
      for (int j = 0; j < 4; j++) {
        s[r][j] = fmaf(q4.x, k4[j].x, s[r][j]);
        s[r][j] = fmaf(q4.y, k4[j].y, s[r][j]);
        s[r][j] = fmaf(q4.z, k4[j].z, s[r][j]);
        s[r][j] = fmaf(q4.w, k4[j].w, s[r][j]);
      }
    }
  }
#pragma unroll
  for (int r = 0; r < 8; r++) {
    const int n = n0 + r0 + r;
    const float* rp = rpb + (long)n * Mm;
    float sc[4];
#pragma unroll
    for (int j = 0; j < 4; j++) sc[j] = fmaf(s[r][j], SCALEf, rp[lane + j * 64]);
    float mx = fmaxf(fmaxf(sc[0], sc[1]), fmaxf(sc[2], sc[3]));
    mx = wave_max(mx);
    float e[4], sum = 0.f;
#pragma unroll
    for (int j = 0; j < 4; j++) { e[j] = __expf(sc[j] - mx); sum += e[j]; }
    sum = wave_sum(sum);
    const float inv = 1.f / sum;
    unsigned short* ap = attn + (((long)b * NHh + h) * Nn + n) * Mm;
#pragma unroll
    for (int j = 0; j < 4; j++) ap[lane + j * 64] = f2bf(e[j] * inv);
  }
}

// ------------- Gram matrix G[b][36*STP] (line-spread atomics) -------------
__launch_bounds__(256)
__global__ void gram_stats(const unsigned short* __restrict__ attn, float* __restrict__ G)
{
  __shared__ float red[36][4];
  const int b = blockIdx.y, tid = threadIdx.x;
  const unsigned short* ap = attn + (long)b * NHh * NMs + (long)blockIdx.x * 2048 + tid * 8;
  float a[8][8];
#pragma unroll
  for (int h = 0; h < 8; h++) {
    const uint4 v = *(const uint4*)&ap[(long)h * NMs];
    a[h][0] = bflo(v.x); a[h][1] = bfhi(v.x); a[h][2] = bflo(v.y); a[h][3] = bfhi(v.y);
    a[h][4] = bflo(v.z); a[h][5] = bfhi(v.z); a[h][6] = bflo(v.w); a[h][7] = bfhi(v.w);
  }
  float g[36];
  int t = 0;
#pragma unroll
  for (int i = 0; i < 8; i++)
#pragma unroll
    for (int j = i; j < 8; j++, t++) {
      float s = 0.f;
#pragma unroll
      for (int m = 0; m < 8; m++) s = fmaf(a[i][m], a[j][m], s);
      g[t] = s;
    }
  const int lane = tid & 63, wid = tid >> 6;
#pragma unroll
  for (int t2 = 0; t2 < 36; t2++) {
    const float s = wave_sum(g[t2]);
    if (lane == 0) red[t2][wid] = s;
  }
  __syncthreads();
  if (tid < 36)
    atomicAdd(&G[((long)b * 36 + tid) * STP],
              red[tid][0] + red[tid][1] + red[tid][2] + red[tid][3]);
}

// ------------- pass B: expand+gn1(from G)+swish -> conv3x3 -> x2(bf16) + gn2 stats ----
// R13 geometry (one-shot 18-row staging, 72 KB LDS, ONE barrier, TTB=16/512 blocks).
// Inner arithmetic on float2 ext-vectors: channel pair packed -> v_pk_fma_f32.
__launch_bounds__(768)
__global__ void dla_pass_b(const unsigned short* __restrict__ attn,
                           const float* __restrict__ Wexp,
                           const float* __restrict__ g1, const float* __restrict__ b1,
                           const float* __restrict__ G, const float* __restrict__ Wdw,
                           unsigned short* __restrict__ x2, float* __restrict__ stats2c, int b0)
{
  __shared__ __align__(16) unsigned short sl[TTB + 2][NHh][Mm];   // 18 x 4 KB = 72 KB
  const int tid = threadIdx.x;
  const int wv = tid >> 6, lane = tid & 63;
  const int bc = blockIdx.y, b = b0 + bc;
  const int n0 = blockIdx.x * TTB;
  const int c0 = wv * 2;
  const int g = c0 >> 3;
  // gn1 stats from Gram matrix (mean exact: softmax rows sum to 1)
  float mu, rs;
  {
    const float* Gb = G + (long)b * 36 * STP;
    float sum = 0.f, sumsq = 0.f;
    for (int c = g * 8; c < g * 8 + 8; c++) {
      float w[8];
#pragma unroll
      for (int h = 0; h < 8; h++) w[h] = Wexp[c * 8 + h];
      float wsu = 0.f;
#pragma unroll
      for (int h = 0; h < 8; h++) wsu += w[h];
      sum += wsu;
      float s2 = 0.f;
      int t = 0;
#pragma unroll
      for (int i = 0; i < 8; i++)
#pragma unroll
        for (int j = i; j < 8; j++, t++) {
          const float f = (i == j) ? 1.f : 2.f;
          s2 = fmaf(f * w[i] * w[j], Gb[t * STP], s2);
        }
      sumsq += s2;
    }
    const float cnt = 8.f * NMs;
    mu = sum * ((float)Nn / cnt);
    const float var = sumsq / cnt - mu * mu;
    rs = rsqrtf(var + EPSf);
  }
  // channel-pair (v2f) weights: lane .x -> c0, lane .y -> c0+1
  v2f we2[8], wd2[9], B12;
  {
    const float A10 = rs * g1[c0], A11 = rs * g1[c0 + 1];
    B12.x = b1[c0] - mu * A10;
    B12.y = b1[c0 + 1] - mu * A11;
#pragma unroll
    for (int h = 0; h < NHh; h++) {
      we2[h].x = Wexp[c0 * NHh + h] * A10;
      we2[h].y = Wexp[(c0 + 1) * NHh + h] * A11;
    }
#pragma unroll
    for (int k = 0; k < 9; k++) {
      wd2[k].x = Wdw[c0 * 9 + k];
      wd2[k].y = Wdw[(c0 + 1) * 9 + k];
    }
  }
  // stage all 18 rows: 18*8*32 = 4608 uint4s, 6 per thread, coalesced
  const unsigned short* ab = attn + (long)b * NHh * NMs;
#pragma unroll
  for (int k = 0; k < 6; k++) {
    const int f = tid + k * 768;
    const int row = f >> 8;
    const int rem = f & 255;
    const int h = rem >> 5, seg = rem & 31;
    const int nn = n0 - 1 + row;
    uint4 v = make_uint4(0u, 0u, 0u, 0u);
    if (nn >= 0 && nn < Nn)
      v = *(const uint4*)&ab[(long)h * NMs + (long)nn * Mm + seg * 8];
    *(uint4*)&sl[row][h][seg * 8] = v;
  }
  __syncthreads();   // the only barrier: all rows staged
  v2f s1p[4] = {}, s2p[4] = {};
  v2f smp = {0.f, 0.f}, sqp = {0.f, 0.f};
  for (int r = -1; r <= TTB; r++) {
    const int nn = n0 + r;
    const bool rowv = (nn >= 0 && nn < Nn);
    v2f xp[4];
    if (rowv) {
#pragma unroll
      for (int mi = 0; mi < 4; mi++) xp[mi] = B12;
#pragma unroll
      for (int h = 0; h < NHh; h++) {
        const ushort4 v = *(const ushort4*)&sl[r + 1][h][lane * 4];
        const v2f w = we2[h];
        xp[0] += w * bfup(v.x);
        xp[1] += w * bfup(v.y);
        xp[2] += w * bfup(v.z);
        xp[3] += w * bfup(v.w);
      }
#pragma unroll
      for (int mi = 0; mi < 4; mi++) xp[mi] = swish2(xp[mi]);
    } else {
#pragma unroll
      for (int mi = 0; mi < 4; mi++) xp[mi] = (v2f){0.f, 0.f};
    }
    // horizontal halo via shuffles (per component; shfl is 32-bit)
    v2f xl, xr;
    xl.x = __shfl_up(xp[3].x, 1);  xl.y = __shfl_up(xp[3].y, 1);
    xr.x = __shfl_down(xp[0].x, 1); xr.y = __shfl_down(xp[0].y, 1);
    if (lane == 0)  { xl.x = 0.f; xl.y = 0.f; }
    if (lane == 63) { xr.x = 0.f; xr.y = 0.f; }
    const v2f L[4] = {xl, xp[0], xp[1], xp[2]};
    const v2f R[4] = {xp[1], xp[2], xp[3], xr};
    v2f y[4];
#pragma unroll
    for (int mi = 0; mi < 4; mi++) {
      const v2f u0 = wd2[0] * L[mi] + wd2[1] * xp[mi] + wd2[2] * R[mi];
      const v2f u1 = wd2[3] * L[mi] + wd2[4] * xp[mi] + wd2[5] * R[mi];
      const v2f u2 = wd2[6] * L[mi] + wd2[7] * xp[mi] + wd2[8] * R[mi];
      y[mi] = s2p[mi] + u2;
      s2p[mi] = s1p[mi] + u1;
      s1p[mi] = u0;
    }
    if (r >= 1) {
#pragma unroll
      for (int mi = 0; mi < 4; mi++) {
        smp += y[mi];
        sqp += y[mi] * y[mi];
      }
      const int nw = n0 + r - 1;
      ushort4 st0, st1;
      st0.x = f2bf(y[0].x); st0.y = f2bf(y[1].x); st0.z = f2bf(y[2].x); st0.w = f2bf(y[3].x);
      st1.x = f2bf(y[0].y); st1.y = f2bf(y[1].y); st1.z = f2bf(y[2].y); st1.w = f2bf(y[3].y);
      unsigned short* xq = x2 + ((long)(bc * Nn + nw) * HIDh + c0) * Mm + lane * 4;
      *(ushort4*)xq = st0;
      *(ushort4*)(xq + Mm) = st1;
    }
  }
  {
    const float vs0 = wave_sum(smp.x), vq0 = wave_sum(sqp.x);
    const float vs1 = wave_sum(smp.y), vq1 = wave_sum(sqp.y);
    if (lane == 0) {
      atomicAdd(&stats2c[((long)b * HIDh + c0) * STP], vs0);
      atomicAdd(&stats2c[((long)b * HIDh + c0) * STP + 1], vq0);
      atomicAdd(&stats2c[((long)b * HIDh + c0 + 1) * STP], vs1);
      atomicAdd(&stats2c[((long)b * HIDh + c0 + 1) * STP + 1], vq1);
    }
  }
}

// ------------- pass C: gn2+swish + 1x1 reduce -> a2(bf16) + partial gn3 stats -------
__launch_bounds__(256)
__global__ void dla_pass_c(const unsigned short* __restrict__ x2, const float* __restrict__ g2,
                           const float* __restrict__ b2, const float* __restrict__ stats2c,
                           const float* __restrict__ Wred, unsigned short* __restrict__ a2,
                           float* __restrict__ partial3, int b0)
{
  __shared__ float wA[HIDh], wB[HIDh], wrs[HIDh][NHh];
  __shared__ float red2[2][4];
  const int tid = threadIdx.x;
  const int wv = tid >> 6, lane = tid & 63;
  const int bc = blockIdx.y, b = b0 + bc;
  if (tid < HIDh) {
    const int c = tid, g = c >> 3;
    float s = 0.f, q = 0.f;
#pragma unroll
    for (int cc = 0; cc < 8; cc++) {
      s += stats2c[((long)b * HIDh + g * 8 + cc) * STP];
      q += stats2c[((long)b * HIDh + g * 8 + cc) * STP + 1];
    }
    const float cnt = 8.f * NMs;
    const float mu = s / cnt;
    const float var = q / cnt - mu * mu;
    const float A2 = rsqrtf(var + EPSf) * g2[c];
    wA[c] = A2; wB[c] = b2[c] - mu * A2;
  }
  if (tid < HIDh * NHh) {
    const int c = tid >> 3, h = tid & 7;
    wrs[c][h] = Wred[h * HIDh + c];
  }
  __syncthreads();
  const int rsel = lane >> 5, ms = lane & 31;
  const int n = blockIdx.x * 8 + wv * 2 + rsel;
  const unsigned short* xp = x2 + (long)(bc * Nn + n) * HIDh * Mm + ms * 8;
  float red[NHh][8] = {};
#pragma unroll
  for (int c = 0; c < HIDh; c++) {
    const uint4 xv = *(const uint4*)&xp[c * Mm];
    const float Ac = wA[c], Bc = wB[c];
    float sw[8];
    sw[0] = swish_(fmaf(bflo(xv.x), Ac, Bc));
    sw[1] = swish_(fmaf(bfhi(xv.x), Ac, Bc));
    sw[2] = swish_(fmaf(bflo(xv.y), Ac, Bc));
    sw[3] = swish_(fmaf(bfhi(xv.y), Ac, Bc));
    sw[4] = swish_(fmaf(bflo(xv.z), Ac, Bc));
    sw[5] = swish_(fmaf(bfhi(xv.z), Ac, Bc));
    sw[6] = swish_(fmaf(bflo(xv.w), Ac, Bc));
    sw[7] = swish_(fmaf(bfhi(xv.w), Ac, Bc));
#pragma unroll
    for (int h = 0; h < NHh; h++) {
      const float w = wrs[c][h];
#pragma unroll
      for (int mi = 0; mi < 8; mi++) red[h][mi] = fmaf(w, sw[mi], red[h][mi]);
    }
  }
  float s3 = 0.f, q3 = 0.f;
#pragma unroll
  for (int h = 0; h < NHh; h++) {
    uint4 st;
    st.x = pk2bf(red[h][0], red[h][1]);
    st.y = pk2bf(red[h][2], red[h][3]);
    st.z = pk2bf(red[h][4], red[h][5]);
    st.w = pk2bf(red[h][6], red[h][7]);
    *(uint4*)&a2[(((long)b * NHh + h) * Nn + n) * Mm + ms * 8] = st;
#pragma unroll
    for (int mi = 0; mi < 8; mi++) {
      s3 += red[h][mi]; q3 = fmaf(red[h][mi], red[h][mi], q3);
    }
  }
  s3 = wave_sum(s3); q3 = wave_sum(q3);
  if (lane == 0) { red2[0][wv] = s3; red2[1][wv] = q3; }
  __syncthreads();
  if (tid < 2) {
    float t = red2[tid][0] + red2[tid][1] + red2[tid][2] + red2[tid][3];
    partial3[((long)b * 128 + blockIdx.x) * 2 + tid] = t;
  }
}

// ------------- finalize gn3 stats: reduce partial3[b][128][2] -> stats3[b][2] -------
__launch_bounds__(128)
__global__ void finalize_stats3(const float* __restrict__ partial3, float* __restrict__ stats3)
{
  __shared__ float red2[2][2];
  const int b = blockIdx.x, tid = threadIdx.x;
  const int lane = tid & 63, wv = tid >> 6;
  float s = partial3[((long)b * 128 + tid) * 2];
  float q = partial3[((long)b * 128 + tid) * 2 + 1];
  s = wave_sum(s); q = wave_sum(q);
  if (lane == 0) { red2[0][wv] = s; red2[1][wv] = q; }
  __syncthreads();
  if (tid < 2)
    stats3[b * 2 + tid] = red2[tid][0] + red2[tid][1];
}

// ------------- pv_out: gn3 (folded) + PV -> oT[b,c,n] (coalesced) -------------
__launch_bounds__(256)
__global__ void pv_out(const unsigned short* __restrict__ a2, const float* __restrict__ vb,
                       const float* __restrict__ sv, const float* __restrict__ stats3,
                       const float* __restrict__ g3, const float* __restrict__ b3,
                       float* __restrict__ o)
{
  __shared__ __align__(16) float As[16 * 260];
  __shared__ __align__(16) float Vs[Mm * HDd];
  const int b = blockIdx.z, h = blockIdx.y, n0 = blockIdx.x * 256;
  const int tid = threadIdx.x;
  const float* vp = vb + ((long)b * NHh + h) * Mm * HDd;
#pragma unroll
  for (int u = 0; u < 8; u++) {
    const int f = tid + u * 256;
    ((float4*)Vs)[f] = ((const float4*)vp)[f];
  }
  const unsigned short* ap = a2 + (((long)b * NHh + h) * Nn + n0) * Mm;
  const int tx = tid & 63, ty = tid >> 6;
  float acc[4][8] = {};
  for (int k0 = 0; k0 < Mm; k0 += 16) {
    __syncthreads();
#pragma unroll
    for (int u = 0; u < 2; u++) {
      const int s = tid + u * 256;
      const int row = s >> 1, half = (s & 1) * 8;
      const uint4 pk = *(const uint4*)(ap + (long)row * Mm + k0 + half);
      As[(half + 0) * 260 + row] = bflo(pk.x);
      As[(half + 1) * 260 + row] = bfhi(pk.x);
      As[(half + 2) * 260 + row] = bflo(pk.y);
      As[(half + 3) * 260 + row] = bfhi(pk.y);
      As[(half + 4) * 260 + row] = bflo(pk.z);
      As[(half + 5) * 260 + row] = bfhi(pk.z);
      As[(half + 6) * 260 + row] = bflo(pk.w);
      As[(half + 7) * 260 + row] = bfhi(pk.w);
    }
    __syncthreads();
#pragma unroll
    for (int k = 0; k < 16; k++) {
      const float4 a4 = *(const float4*)&As[k * 260 + tx * 4];
      const float4 w0 = *(const float4*)&Vs[(k0 + k) * HDd + ty * 8];
      const float4 w1 = *(const float4*)&Vs[(k0 + k) * HDd + ty * 8 + 4];
      const float av[4] = {a4.x, a4.y, a4.z, a4.w};
      const float vv[8] = {w0.x, w0.y, w0.z, w0.w, w1.x, w1.y, w1.z, w1.w};
#pragma unroll
      for (int u = 0; u < 4; u++)
#pragma unroll
        for (int v = 0; v < 8; v++)
          acc[u][v] = fmaf(av[u], vv[v], acc[u][v]);
    }
  }
  const float cnt = (float)(NHh * NMs);
  const float mu = stats3[b * 2] / cnt;
  const float var = stats3[b * 2 + 1] / cnt - mu * mu;
  const float r3 = rsqrtf(var + EPSf);
  const float alpha = r3 * g3[h];
  const float beta = b3[h] - mu * alpha;
  float svv[8];
#pragma unroll
  for (int v = 0; v < 8; v++) svv[v] = sv[((long)b * NHh + h) * HDd + ty * 8 + v];
#pragma unroll
  for (int v = 0; v < 8; v++) {
    const int c = h * HDd + ty * 8 + v;
    const float bv = beta * svv[v];
    float4 r4 = make_float4(fmaf(alpha, acc[0][v], bv), fmaf(alpha, acc[1][v], bv),
                            fmaf(alpha, acc[2][v], bv), fmaf(alpha, acc[3][v], bv));
    *(float4*)&o[((long)b * Cc + c) * Nn + n0 + tx * 4] = r4;
  }
}

extern "C" void kernel_launch(void* const* d_in, const int* in_sizes, int n_in,
                              void* d_out, int out_size, void* d_ws, size_t ws_size,
                              hipStream_t stream) {
  const float* q    = (const float*)d_in[0];
  const float* kv   = (const float*)d_in[1];
  const float* Wq   = (const float*)d_in[2];
  const float* Wkv  = (const float*)d_in[3];
  const float* Wp   = (const float*)d_in[4];
  const float* bp   = (const float*)d_in[5];
  const float* rpb  = (const float*)d_in[6];
  const float* Wexp = (const float*)d_in[7];
  const float* g1   = (const float*)d_in[8];
  const float* b1   = (const float*)d_in[9];
  const float* Wdw  = (const float*)d_in[10];
  const float* g2   = (const float*)d_in[11];
  const float* b2   = (const float*)d_in[12];
  const float* Wred = (const float*)d_in[13];
  const float* g3   = (const float*)d_in[14];
  const float* b3   = (const float*)d_in[15];
  float* out = (float*)d_out;

  float* ws = (float*)d_ws;
  size_t off = 0;
  auto alloc = [&](size_t n) { float* p = ws + off; off += n; return p; };
  float* attnf   = alloc((size_t)Bb * NHh * NMs / 2);      // 67.1 MB (bf16)
  float* a2f     = alloc((size_t)Bb * NHh * NMs / 2);      // 67.1 MB (bf16)
  float* big     = alloc((size_t)CHUNK * HIDh * NMs / 2);  // 100.7 MB: qhT -> x2 -> oT
  float* kbuf    = alloc((size_t)Bb * NHh * Mm * HDd);     // 4.2 MB
  float* vbuf    = alloc((size_t)Bb * NHh * Mm * HDd);     // 4.2 MB
  float* sv      = alloc((size_t)Bb * NHh * HDd);
  float* G       = alloc((size_t)Bb * 36 * STP);           // line-spread
  float* stats2c = alloc((size_t)Bb * HIDh * STP);         // line-spread
  float* stats3  = alloc(Bb * 2);
  float* partial3= alloc((size_t)Bb * 128 * 2);            // fully overwritten, no memset
  unsigned short* attn = (unsigned short*)attnf;
  unsigned short* a2 = (unsigned short*)a2f;
  float* qhT = big;                           // dead after attn_softmax
  unsigned short* x2 = (unsigned short*)big;  // alive during DLA chunk loop
  float* oT = big;                            // alive after last pass C

  // zero only the atomic-accumulated buffers (G | stats2c are contiguous)
  hipMemsetAsync(G, 0, (size_t)(Bb * 36 * STP + Bb * HIDh * STP) * sizeof(float), stream);

  gemm_tn<0><<<dim3(Nn / 64, Cc / 64, Bb), 256, 0, stream>>>(
      q, Wq, nullptr, qhT, nullptr, Cc, (long)Cc * Nn, Nn, 1);
  gemm_tn<1><<<dim3(Mm / 64, 512 / 64, Bb), 256, 0, stream>>>(
      kv, Wkv, nullptr, kbuf, vbuf, Cc, (long)Cc * Mm, Mm, 1);
  compute_sv<<<dim3(Bb * NHh), 256, 0, stream>>>(vbuf, sv);
  attn_softmax<<<dim3(Nn / 32, NHh, Bb), 256, 0, stream>>>(qhT, kbuf, rpb, attn);
  gram_stats<<<dim3(NMs / 2048, Bb), 256, 0, stream>>>(attn, G);

  for (int b0 = 0; b0 < Bb; b0 += CHUNK) {
    dla_pass_b<<<dim3(Nn / TTB, CHUNK), 768, 0, stream>>>(
        attn, Wexp, g1, b1, G, Wdw, x2, stats2c, b0);
    dla_pass_c<<<dim3(Nn / 8, CHUNK), 256, 0, stream>>>(
        x2, g2, b2, stats2c, Wred, a2, partial3, b0);
  }
  finalize_stats3<<<dim3(Bb), 128, 0, stream>>>(partial3, stats3);

  pv_out<<<dim3(Nn / 256, NHh, Bb), 256, 0, stream>>>(a2, vbuf, sv, stats3, g3, b3, oT);
  gemm_tn<2><<<dim3(Nn / 64, Cc / 64, Bb), 256, 0, stream>>>(
      oT, Wp, bp, out, nullptr, Cc, (long)Cc * Nn, Nn, 1);
}